// Round 1
// baseline (243.115 us; speedup 1.0000x reference)
//
#include <hip/hip_runtime.h>
#include <stdint.h>

#define NUM_CLASSES 81
#define MAX_BOXES 300
#define NEG_SCORE (-1000000000.0f)
#define IOU_THR 0.4f
#define MMAX 4096
#define MWORDS (MMAX / 64)
#define OUT_TOTAL (MAX_BOXES * 4 + MAX_BOXES * NUM_CLASSES)  // 25500

// ---- workspace layout (bytes) ----
static constexpr size_t OFF_SCORES = 0;               // 300000 * 4 = 1.2 MB
static constexpr size_t OFF_COARSE = 0x200000;        // 256 u32
static constexpr size_t OFF_FINE   = 0x201000;        // 256 u32
static constexpr size_t OFF_CTRL   = 0x202000;        // [0]=cand_count [1]=acc_count
static constexpr size_t OFF_RANK   = 0x203000;        // MMAX u32
static constexpr size_t OFF_KEYS   = 0x208000;        // MMAX u64
static constexpr size_t OFF_CIDX   = 0x210000;        // MMAX int
static constexpr size_t OFF_CBOX   = 0x214000;        // MMAX float4
static constexpr size_t OFF_ACC    = 0x224000;        // 300 int
static constexpr size_t OFF_MATRIX = 0x228000;        // MMAX * MWORDS u64 = 2 MB

__device__ __forceinline__ uint32_t float_ordered(float f) {
    uint32_t b = __float_as_uint(f);
    return (b & 0x80000000u) ? ~b : (b | 0x80000000u);
}

__device__ __forceinline__ uint64_t shfl_u64(uint64_t v, int src) {
    int lo = __shfl((int)(uint32_t)v, src);
    int hi = __shfl((int)(uint32_t)(v >> 32), src);
    return ((uint64_t)(uint32_t)hi << 32) | (uint32_t)lo;
}

// Z: zero hists / counters / ranks (re-run every call: determinism under graph replay)
__global__ void init_kernel(uint32_t* coarse, uint32_t* fine, uint32_t* ctrl, uint32_t* rank) {
    int t = blockIdx.x * blockDim.x + threadIdx.x;
    if (t < 256) { coarse[t] = 0; fine[t] = 0; }
    if (t < 8) ctrl[t] = 0;
    for (int r = t; r < MMAX; r += gridDim.x * blockDim.x) rank[r] = 0;
}

// A: wave-per-box max over 81 classes. score = NEG if class0 is the (first) argmax.
__global__ void score_kernel(const float* __restrict__ cls, float* __restrict__ scores, int n) {
    int wave = (blockIdx.x * blockDim.x + threadIdx.x) >> 6;
    int lane = threadIdx.x & 63;
    if (wave >= n) return;
    const float* row = cls + (size_t)wave * NUM_CLASSES;
    float v0 = row[lane];
    float m = v0;
    if (lane < NUM_CLASSES - 64) m = fmaxf(m, row[64 + lane]);
    #pragma unroll
    for (int off = 32; off; off >>= 1) m = fmaxf(m, __shfl_xor(m, off));
    if (lane == 0) {
        scores[wave] = (v0 == m) ? NEG_SCORE : m;  // v0 <= m always; equality => argmax==0
    }
}

// B: coarse 256-bin histogram on top-8 ordered bits (LDS aggregate -> global)
__global__ void coarse_hist_kernel(const float* __restrict__ scores, uint32_t* __restrict__ coarse, int n) {
    __shared__ uint32_t h[256];
    for (int t = threadIdx.x; t < 256; t += blockDim.x) h[t] = 0;
    __syncthreads();
    for (int i = blockIdx.x * blockDim.x + threadIdx.x; i < n; i += gridDim.x * blockDim.x) {
        uint32_t o = float_ordered(scores[i]);
        atomicAdd(&h[o >> 24], 1u);
    }
    __syncthreads();
    for (int t = threadIdx.x; t < 256; t += blockDim.x)
        if (h[t]) atomicAdd(&coarse[t], h[t]);
}

// pick the coarse bin C containing the Mmax-th element; returns -1 if total <= Mmax
__device__ __forceinline__ int select_coarse(const uint32_t* coarse, uint32_t* above_out) {
    uint32_t s = 0;
    for (int c = 255; c >= 0; --c) {
        uint32_t sc = s + coarse[c];
        if (sc > MMAX) { *above_out = s; return c; }
        s = sc;
    }
    *above_out = s;
    return -1;
}

// D: fine 256-bin histogram of elements inside coarse bin C (next 8 ordered bits)
__global__ void fine_hist_kernel(const float* __restrict__ scores, const uint32_t* __restrict__ coarse,
                                 uint32_t* __restrict__ fine, int n) {
    __shared__ int sC;
    __shared__ uint32_t h[256];
    if (threadIdx.x == 0) {
        uint32_t above;
        sC = select_coarse(coarse, &above);
    }
    for (int t = threadIdx.x; t < 256; t += blockDim.x) h[t] = 0;
    __syncthreads();
    int C = sC;
    if (C < 0) return;  // cannot happen with 300k boxes, but safe
    for (int i = blockIdx.x * blockDim.x + threadIdx.x; i < n; i += gridDim.x * blockDim.x) {
        uint32_t o = float_ordered(scores[i]);
        if ((int)(o >> 24) == C) atomicAdd(&h[(o >> 16) & 255u], 1u);
    }
    __syncthreads();
    for (int t = threadIdx.x; t < 256; t += blockDim.x)
        if (h[t]) atomicAdd(&fine[t], h[t]);
}

// F: compute 16-bit threshold (max candidates <= MMAX), compact keys = (ordered<<32)|~idx
__global__ void compact_kernel(const float* __restrict__ scores, const uint32_t* __restrict__ coarse,
                               const uint32_t* __restrict__ fine, uint32_t* __restrict__ ctrl,
                               uint64_t* __restrict__ keys, int n) {
    __shared__ uint32_t sThr;
    if (threadIdx.x == 0) {
        uint32_t above;
        int C = select_coarse(coarse, &above);
        uint32_t thr;
        if (C < 0) {
            thr = 0;
        } else {
            uint32_t R = MMAX - above;
            uint32_t g = 0, F = 0;
            for (int f = 255; f >= 0; --f) {
                uint32_t gf = g + fine[f];
                if (gf > R) { F = (uint32_t)f + 1u; break; }
                g = gf;
            }
            thr = ((uint32_t)C << 8) | F;
        }
        sThr = thr;
    }
    __syncthreads();
    uint32_t thr = sThr;
    for (int i = blockIdx.x * blockDim.x + threadIdx.x; i < n; i += gridDim.x * blockDim.x) {
        uint32_t o = float_ordered(scores[i]);
        if ((o >> 16) >= thr) {
            uint32_t pos = atomicAdd(&ctrl[0], 1u);
            if (pos < MMAX)
                keys[pos] = ((uint64_t)o << 32) | (uint32_t)(~(uint32_t)i);
        }
    }
}

// G1: brute-force rank: rank[c] = #{j : key_j > key_c}, tiled 256x256 via LDS
__global__ void rank_partial_kernel(const uint64_t* __restrict__ keys, const uint32_t* __restrict__ ctrl,
                                    uint32_t* __restrict__ rank) {
    __shared__ uint64_t kk[256];
    int M = (int)ctrl[0]; if (M > MMAX) M = MMAX;
    int cbase = blockIdx.x * 256;
    int jbase = blockIdx.y * 256;
    if (cbase >= M || jbase >= M) return;
    int t = threadIdx.x;
    int j = jbase + t;
    kk[t] = (j < M) ? keys[j] : 0ull;  // 0 never exceeds a candidate key (top bit set)
    __syncthreads();
    int c = cbase + t;
    if (c >= M) return;
    uint64_t k = keys[c];
    int cnt = 0;
    #pragma unroll 8
    for (int u = 0; u < 256; ++u) cnt += (kk[u] > k) ? 1 : 0;
    if (cnt) atomicAdd(&rank[c], (uint32_t)cnt);
}

// G2: scatter into sorted order; gather candidate boxes
__global__ void scatter_kernel(const uint64_t* __restrict__ keys, const uint32_t* __restrict__ rank,
                               const uint32_t* __restrict__ ctrl, const float* __restrict__ boxes,
                               int* __restrict__ csorted_idx, float4* __restrict__ csorted_box) {
    int M = (int)ctrl[0]; if (M > MMAX) M = MMAX;
    int c = blockIdx.x * blockDim.x + threadIdx.x;
    if (c >= M) return;
    uint64_t k = keys[c];
    uint32_t r = rank[c];
    uint32_t idx = ~(uint32_t)k;
    csorted_idx[r] = (int)idx;
    csorted_box[r] = *(const float4*)(boxes + (size_t)idx * 4);
}

// H: pairwise IoU suppression bitmask (row i, bit j): exact reference float math
__global__ void matrix_kernel(const float4* __restrict__ cbox, const uint32_t* __restrict__ ctrl,
                              uint64_t* __restrict__ matrix) {
    int i = blockIdx.x;
    int M = (int)ctrl[0]; if (M > MMAX) M = MMAX;
    if (i >= M) return;
    int lane = threadIdx.x;  // 64 threads
    float4 bi = cbox[i];
    float ai = fmaxf(bi.z - bi.x, 0.f) * fmaxf(bi.w - bi.y, 0.f);
    for (int w = 0; w < MWORDS; ++w) {
        int j = (w << 6) | lane;
        bool sup = false;
        if (j < M) {
            float4 bj = cbox[j];
            float aj = fmaxf(bj.z - bj.x, 0.f) * fmaxf(bj.w - bj.y, 0.f);
            float xx1 = fmaxf(bi.x, bj.x);
            float yy1 = fmaxf(bi.y, bj.y);
            float xx2 = fminf(bi.z, bj.z);
            float yy2 = fminf(bi.w, bj.w);
            float inter = fmaxf(xx2 - xx1, 0.f) * fmaxf(yy2 - yy1, 0.f);
            float uni = ai + aj - inter;
            float iou = inter / fmaxf(uni, 1e-8f);
            sup = iou > IOU_THR;
        }
        uint64_t word = __ballot(sup ? 1 : 0);
        if (lane == w) matrix[(size_t)i * MWORDS + w] = word;
    }
}

// I: sequential greedy scan, one wave; removed bitmask = 1 u64/lane; 8-deep row prefetch
__global__ void scan_kernel(const uint64_t* __restrict__ matrix, uint32_t* __restrict__ ctrl,
                            int* __restrict__ accepted) {
    const int lane = threadIdx.x;
    int M = (int)ctrl[0]; if (M > MMAX) M = MMAX;
    uint64_t removed = 0;
    int acc = 0;
    uint64_t pf0, pf1, pf2, pf3, pf4, pf5, pf6, pf7;
    pf0 = (0 < M) ? matrix[(size_t)0 * MWORDS + lane] : 0ull;
    pf1 = (1 < M) ? matrix[(size_t)1 * MWORDS + lane] : 0ull;
    pf2 = (2 < M) ? matrix[(size_t)2 * MWORDS + lane] : 0ull;
    pf3 = (3 < M) ? matrix[(size_t)3 * MWORDS + lane] : 0ull;
    pf4 = (4 < M) ? matrix[(size_t)4 * MWORDS + lane] : 0ull;
    pf5 = (5 < M) ? matrix[(size_t)5 * MWORDS + lane] : 0ull;
    pf6 = (6 < M) ? matrix[(size_t)6 * MWORDS + lane] : 0ull;
    pf7 = (7 < M) ? matrix[(size_t)7 * MWORDS + lane] : 0ull;

#define SCAN_STEP(PF, U)                                                        \
    {                                                                           \
        int i = base + (U);                                                     \
        if (i < M && acc < MAX_BOXES) {                                         \
            uint64_t row = PF;                                                  \
            int nx = i + 8;                                                     \
            PF = (nx < M) ? matrix[(size_t)nx * MWORDS + lane] : 0ull;          \
            uint64_t wrd = shfl_u64(removed, i >> 6);                           \
            if (!((wrd >> (i & 63)) & 1ull)) {                                  \
                if (lane == 0) accepted[acc] = i;                               \
                removed |= row;                                                 \
                ++acc;                                                          \
            }                                                                   \
        }                                                                       \
    }

    for (int base = 0; base < M && acc < MAX_BOXES; base += 8) {
        SCAN_STEP(pf0, 0)
        SCAN_STEP(pf1, 1)
        SCAN_STEP(pf2, 2)
        SCAN_STEP(pf3, 3)
        SCAN_STEP(pf4, 4)
        SCAN_STEP(pf5, 5)
        SCAN_STEP(pf6, 6)
        SCAN_STEP(pf7, 7)
    }
#undef SCAN_STEP
    if (lane == 0) ctrl[1] = (uint32_t)acc;
}

// J: write all 25500 outputs (zeros for invalid slots)
__global__ void output_kernel(const float* __restrict__ boxes, const float* __restrict__ cls,
                              const int* __restrict__ csorted_idx, const int* __restrict__ accepted,
                              const uint32_t* __restrict__ ctrl, float* __restrict__ out, int total) {
    int e = blockIdx.x * blockDim.x + threadIdx.x;
    if (e >= total) return;
    int acc = (int)ctrl[1];
    float val = 0.0f;
    if (e < MAX_BOXES * 4) {
        int s = e >> 2, f = e & 3;
        if (s < acc) {
            int orig = csorted_idx[accepted[s]];
            val = boxes[(size_t)orig * 4 + f];
        }
    } else {
        int e2 = e - MAX_BOXES * 4;
        int s = e2 / NUM_CLASSES;
        int c = e2 - s * NUM_CLASSES;
        if (s < acc) {
            int orig = csorted_idx[accepted[s]];
            val = cls[(size_t)orig * NUM_CLASSES + c];
        }
    }
    out[e] = val;
}

extern "C" void kernel_launch(void* const* d_in, const int* in_sizes, int n_in,
                              void* d_out, int out_size, void* d_ws, size_t ws_size,
                              hipStream_t stream) {
    const float* boxes = (const float*)d_in[0];
    const float* cls   = (const float*)d_in[1];
    float* out = (float*)d_out;
    const int N = in_sizes[0] / 4;

    char* ws = (char*)d_ws;
    float*     scores      = (float*)(ws + OFF_SCORES);
    uint32_t*  coarse      = (uint32_t*)(ws + OFF_COARSE);
    uint32_t*  fine        = (uint32_t*)(ws + OFF_FINE);
    uint32_t*  ctrl        = (uint32_t*)(ws + OFF_CTRL);
    uint32_t*  rank        = (uint32_t*)(ws + OFF_RANK);
    uint64_t*  keys        = (uint64_t*)(ws + OFF_KEYS);
    int*       csorted_idx = (int*)(ws + OFF_CIDX);
    float4*    csorted_box = (float4*)(ws + OFF_CBOX);
    int*       accepted    = (int*)(ws + OFF_ACC);
    uint64_t*  matrix      = (uint64_t*)(ws + OFF_MATRIX);

    init_kernel<<<16, 256, 0, stream>>>(coarse, fine, ctrl, rank);
    score_kernel<<<(N + 3) / 4, 256, 0, stream>>>(cls, scores, N);
    coarse_hist_kernel<<<256, 256, 0, stream>>>(scores, coarse, N);
    fine_hist_kernel<<<256, 256, 0, stream>>>(scores, coarse, fine, N);
    compact_kernel<<<512, 256, 0, stream>>>(scores, coarse, fine, ctrl, keys, N);
    rank_partial_kernel<<<dim3(MMAX / 256, MMAX / 256), 256, 0, stream>>>(keys, ctrl, rank);
    scatter_kernel<<<MMAX / 256, 256, 0, stream>>>(keys, rank, ctrl, boxes, csorted_idx, csorted_box);
    matrix_kernel<<<MMAX, 64, 0, stream>>>(csorted_box, ctrl, matrix);
    scan_kernel<<<1, 64, 0, stream>>>(matrix, ctrl, accepted);
    output_kernel<<<(out_size + 255) / 256, 256, 0, stream>>>(boxes, cls, csorted_idx, accepted,
                                                              ctrl, out, out_size);
}

// Round 2
// 167.567 us; speedup vs baseline: 1.4509x; 1.4509x over previous
//
#include <hip/hip_runtime.h>
#include <stdint.h>

#define NUM_CLASSES 81
#define MAX_BOXES 300
#define NEG_SCORE (-1000000000.0f)
#define IOU_THR 0.4f
#define MMAX 4096
#define MWORDS (MMAX / 64)

// ---- workspace layout (bytes) ----
static constexpr size_t OFF_SCORES = 0;               // 300000 * 4 = 1.2 MB
static constexpr size_t OFF_CAREA  = 0x1F0000;        // MMAX f32 (16 KB, ends 0x1F4000)
static constexpr size_t OFF_COARSE = 0x200000;        // 256 u32
static constexpr size_t OFF_FINE   = 0x201000;        // 256 u32
static constexpr size_t OFF_CTRL   = 0x202000;        // [0]=cand_count [1]=acc_count
static constexpr size_t OFF_RANK   = 0x203000;        // MMAX u32
static constexpr size_t OFF_KEYS   = 0x208000;        // MMAX u64
static constexpr size_t OFF_CIDX   = 0x210000;        // MMAX int
static constexpr size_t OFF_CBOX   = 0x214000;        // MMAX float4
static constexpr size_t OFF_ACC    = 0x224000;        // 300 int
static constexpr size_t OFF_MATRIX = 0x228000;        // MMAX * MWORDS u64 = 2 MB (ends 0x428000)

__device__ __forceinline__ uint32_t float_ordered(float f) {
    uint32_t b = __float_as_uint(f);
    return (b & 0x80000000u) ? ~b : (b | 0x80000000u);
}

__device__ __forceinline__ uint64_t readlane_u64(uint64_t v, int srclane) {
    uint32_t lo = (uint32_t)__builtin_amdgcn_readlane((int)(uint32_t)v, srclane);
    uint32_t hi = (uint32_t)__builtin_amdgcn_readlane((int)(uint32_t)(v >> 32), srclane);
    return ((uint64_t)hi << 32) | lo;
}

// A: wave-per-box max over 81 classes. score = NEG if class0 is the (first) argmax.
// Block 0 additionally zeroes hists / counters / ranks (init fold).
__global__ void score_kernel(const float* __restrict__ cls, float* __restrict__ scores,
                             uint32_t* __restrict__ coarse, uint32_t* __restrict__ fine,
                             uint32_t* __restrict__ ctrl, uint32_t* __restrict__ rank, int n) {
    if (blockIdx.x == 0) {
        int t = threadIdx.x;
        if (t < 256) { coarse[t] = 0; fine[t] = 0; }
        if (t < 8) ctrl[t] = 0;
        for (int r = t; r < MMAX; r += 256) rank[r] = 0;
    }
    int wave = (blockIdx.x * blockDim.x + threadIdx.x) >> 6;
    int lane = threadIdx.x & 63;
    if (wave >= n) return;
    const float* row = cls + (size_t)wave * NUM_CLASSES;
    float v0 = row[lane];
    float m = v0;
    if (lane < NUM_CLASSES - 64) m = fmaxf(m, row[64 + lane]);
    #pragma unroll
    for (int off = 32; off; off >>= 1) m = fmaxf(m, __shfl_xor(m, off));
    if (lane == 0) {
        scores[wave] = (v0 == m) ? NEG_SCORE : m;  // v0 <= m always; equality => argmax==0
    }
}

// B: coarse 256-bin histogram on top-8 ordered bits (LDS aggregate -> global)
__global__ void coarse_hist_kernel(const float* __restrict__ scores, uint32_t* __restrict__ coarse, int n) {
    __shared__ uint32_t h[256];
    for (int t = threadIdx.x; t < 256; t += blockDim.x) h[t] = 0;
    __syncthreads();
    for (int i = blockIdx.x * blockDim.x + threadIdx.x; i < n; i += gridDim.x * blockDim.x) {
        uint32_t o = float_ordered(scores[i]);
        atomicAdd(&h[o >> 24], 1u);
    }
    __syncthreads();
    for (int t = threadIdx.x; t < 256; t += blockDim.x)
        if (h[t]) atomicAdd(&coarse[t], h[t]);
}

// pick the coarse bin C containing the MMAX-th element; returns -1 if total <= MMAX
__device__ __forceinline__ int select_coarse(const uint32_t* coarse, uint32_t* above_out) {
    uint32_t s = 0;
    for (int c = 255; c >= 0; --c) {
        uint32_t sc = s + coarse[c];
        if (sc > MMAX) { *above_out = s; return c; }
        s = sc;
    }
    *above_out = s;
    return -1;
}

// D: fine 256-bin histogram of elements inside coarse bin C (next 8 ordered bits)
__global__ void fine_hist_kernel(const float* __restrict__ scores, const uint32_t* __restrict__ coarse,
                                 uint32_t* __restrict__ fine, int n) {
    __shared__ int sC;
    __shared__ uint32_t h[256];
    if (threadIdx.x == 0) {
        uint32_t above;
        sC = select_coarse(coarse, &above);
    }
    for (int t = threadIdx.x; t < 256; t += blockDim.x) h[t] = 0;
    __syncthreads();
    int C = sC;
    if (C < 0) return;
    for (int i = blockIdx.x * blockDim.x + threadIdx.x; i < n; i += gridDim.x * blockDim.x) {
        uint32_t o = float_ordered(scores[i]);
        if ((int)(o >> 24) == C) atomicAdd(&h[(o >> 16) & 255u], 1u);
    }
    __syncthreads();
    for (int t = threadIdx.x; t < 256; t += blockDim.x)
        if (h[t]) atomicAdd(&fine[t], h[t]);
}

// F: compute 16-bit threshold (<= MMAX candidates), compact keys = (ordered<<32)|~idx
__global__ void compact_kernel(const float* __restrict__ scores, const uint32_t* __restrict__ coarse,
                               const uint32_t* __restrict__ fine, uint32_t* __restrict__ ctrl,
                               uint64_t* __restrict__ keys, int n) {
    __shared__ uint32_t sThr;
    if (threadIdx.x == 0) {
        uint32_t above;
        int C = select_coarse(coarse, &above);
        uint32_t thr;
        if (C < 0) {
            thr = 0;
        } else {
            uint32_t R = MMAX - above;
            uint32_t g = 0, F = 0;
            for (int f = 255; f >= 0; --f) {
                uint32_t gf = g + fine[f];
                if (gf > R) { F = (uint32_t)f + 1u; break; }
                g = gf;
            }
            thr = ((uint32_t)C << 8) | F;
        }
        sThr = thr;
    }
    __syncthreads();
    uint32_t thr = sThr;
    for (int i = blockIdx.x * blockDim.x + threadIdx.x; i < n; i += gridDim.x * blockDim.x) {
        uint32_t o = float_ordered(scores[i]);
        if ((o >> 16) >= thr) {
            uint32_t pos = atomicAdd(&ctrl[0], 1u);
            if (pos < MMAX)
                keys[pos] = ((uint64_t)o << 32) | (uint32_t)(~(uint32_t)i);
        }
    }
}

// G1: brute-force rank: rank[c] = #{j : key_j > key_c}, tiled 256x256 via LDS
__global__ void rank_partial_kernel(const uint64_t* __restrict__ keys, const uint32_t* __restrict__ ctrl,
                                    uint32_t* __restrict__ rank) {
    __shared__ uint64_t kk[256];
    int M = (int)ctrl[0]; if (M > MMAX) M = MMAX;
    int cbase = blockIdx.x * 256;
    int jbase = blockIdx.y * 256;
    if (cbase >= M || jbase >= M) return;
    int t = threadIdx.x;
    int j = jbase + t;
    kk[t] = (j < M) ? keys[j] : 0ull;  // 0 never exceeds a candidate key (top bit set)
    __syncthreads();
    int c = cbase + t;
    if (c >= M) return;
    uint64_t k = keys[c];
    int cnt = 0;
    #pragma unroll 8
    for (int u = 0; u < 256; ++u) cnt += (kk[u] > k) ? 1 : 0;
    if (cnt) atomicAdd(&rank[c], (uint32_t)cnt);
}

// G2: scatter into sorted order; gather candidate boxes + areas
__global__ void scatter_kernel(const uint64_t* __restrict__ keys, const uint32_t* __restrict__ rank,
                               const uint32_t* __restrict__ ctrl, const float* __restrict__ boxes,
                               int* __restrict__ csorted_idx, float4* __restrict__ csorted_box,
                               float* __restrict__ careas) {
    int M = (int)ctrl[0]; if (M > MMAX) M = MMAX;
    int c = blockIdx.x * blockDim.x + threadIdx.x;
    if (c >= M) return;
    uint64_t k = keys[c];
    uint32_t r = rank[c];
    uint32_t idx = ~(uint32_t)k;
    float4 b = *(const float4*)(boxes + (size_t)idx * 4);
    csorted_idx[r] = (int)idx;
    csorted_box[r] = b;
    careas[r] = fmaxf(b.z - b.x, 0.f) * fmaxf(b.w - b.y, 0.f);
}

// H: pairwise IoU suppression bitmask, upper-triangle words only (w >= i>>6).
// Words < i>>6 are left unwritten: the scan's word pointer is monotone, so those
// bits are never consulted after row i could be accepted.
__global__ void matrix_kernel(const float4* __restrict__ cbox, const float* __restrict__ careas,
                              const uint32_t* __restrict__ ctrl, uint64_t* __restrict__ matrix) {
    int i = blockIdx.x;
    int M = (int)ctrl[0]; if (M > MMAX) M = MMAX;
    if (i >= M) return;
    int lane = threadIdx.x & 63;
    int wave = threadIdx.x >> 6;  // 4 waves per block
    float4 bi = cbox[i];
    float ai = careas[i];
    int w0 = i >> 6;
    for (int w = w0 + wave; w < MWORDS; w += 4) {
        int j = (w << 6) | lane;
        bool sup = false;
        if (j < M) {
            float4 bj = cbox[j];
            float xx1 = fmaxf(bi.x, bj.x);
            float yy1 = fmaxf(bi.y, bj.y);
            float xx2 = fminf(bi.z, bj.z);
            float yy2 = fminf(bi.w, bj.w);
            float inter = fmaxf(xx2 - xx1, 0.f) * fmaxf(yy2 - yy1, 0.f);
            float uni = ai + careas[j] - inter;
            float iou = inter / fmaxf(uni, 1e-8f);
            sup = iou > IOU_THR;
        }
        uint64_t word = __ballot(sup ? 1 : 0);
        if (lane == 0) matrix[(size_t)i * MWORDS + w] = word;
    }
}

// I: sequential greedy scan, one wave. Removed bitmask = 1 u64/lane.
// Unconditional clamp-indexed loads in 32-row ping-pong register blocks (counted
// vmcnt slack); uniform removed-word cached in SGPRs via readlane, refreshed only
// at word boundaries and after accepts.
#define LOADBLK(ARR, b0)                                                       \
    {                                                                          \
        _Pragma("unroll")                                                      \
        for (int r_ = 0; r_ < 32; ++r_) {                                      \
            int row_ = (b0) + r_;                                              \
            row_ = row_ < MMAX ? row_ : MMAX - 1;                              \
            ARR[r_] = matrix[(size_t)row_ * MWORDS + lane];                    \
        }                                                                      \
    }

#define PROCBLK(ARR, b0, REFRESH_AT0)                                          \
    {                                                                          \
        _Pragma("unroll")                                                      \
        for (int r_ = 0; r_ < 32; ++r_) {                                      \
            int i_ = (b0) + r_;                                                \
            if ((REFRESH_AT0) && r_ == 0) {                                    \
                wrd = readlane_u64(removed, i_ >> 6);                          \
            }                                                                  \
            if (i_ < M && acc < MAX_BOXES && !((wrd >> (i_ & 63)) & 1ull)) {   \
                if (lane == 0) accepted[acc] = i_;                             \
                removed |= ARR[r_];                                            \
                wrd = readlane_u64(removed, i_ >> 6);                          \
                ++acc;                                                         \
            }                                                                  \
        }                                                                      \
    }

__global__ void scan_kernel(const uint64_t* __restrict__ matrix, uint32_t* __restrict__ ctrl,
                            int* __restrict__ accepted) {
    const int lane = threadIdx.x;
    int M = (int)ctrl[0]; if (M > MMAX) M = MMAX;
    uint64_t removed = 0;
    uint64_t wrd = 0;
    int acc = 0;
    uint64_t A[32], B[32];

    LOADBLK(A, 0);
    for (int base = 0; base < M && acc < MAX_BOXES; base += 64) {
        LOADBLK(B, base + 32);
        PROCBLK(A, base, true);
        LOADBLK(A, base + 64);
        PROCBLK(B, base + 32, false);
    }
    if (lane == 0) ctrl[1] = (uint32_t)acc;
}
#undef LOADBLK
#undef PROCBLK

// J: write all 25500 outputs (zeros for invalid slots)
__global__ void output_kernel(const float* __restrict__ boxes, const float* __restrict__ cls,
                              const int* __restrict__ csorted_idx, const int* __restrict__ accepted,
                              const uint32_t* __restrict__ ctrl, float* __restrict__ out, int total) {
    int e = blockIdx.x * blockDim.x + threadIdx.x;
    if (e >= total) return;
    int acc = (int)ctrl[1];
    float val = 0.0f;
    if (e < MAX_BOXES * 4) {
        int s = e >> 2, f = e & 3;
        if (s < acc) {
            int orig = csorted_idx[accepted[s]];
            val = boxes[(size_t)orig * 4 + f];
        }
    } else {
        int e2 = e - MAX_BOXES * 4;
        int s = e2 / NUM_CLASSES;
        int c = e2 - s * NUM_CLASSES;
        if (s < acc) {
            int orig = csorted_idx[accepted[s]];
            val = cls[(size_t)orig * NUM_CLASSES + c];
        }
    }
    out[e] = val;
}

extern "C" void kernel_launch(void* const* d_in, const int* in_sizes, int n_in,
                              void* d_out, int out_size, void* d_ws, size_t ws_size,
                              hipStream_t stream) {
    const float* boxes = (const float*)d_in[0];
    const float* cls   = (const float*)d_in[1];
    float* out = (float*)d_out;
    const int N = in_sizes[0] / 4;

    char* ws = (char*)d_ws;
    float*     scores      = (float*)(ws + OFF_SCORES);
    float*     careas      = (float*)(ws + OFF_CAREA);
    uint32_t*  coarse      = (uint32_t*)(ws + OFF_COARSE);
    uint32_t*  fine        = (uint32_t*)(ws + OFF_FINE);
    uint32_t*  ctrl        = (uint32_t*)(ws + OFF_CTRL);
    uint32_t*  rank        = (uint32_t*)(ws + OFF_RANK);
    uint64_t*  keys        = (uint64_t*)(ws + OFF_KEYS);
    int*       csorted_idx = (int*)(ws + OFF_CIDX);
    float4*    csorted_box = (float4*)(ws + OFF_CBOX);
    int*       accepted    = (int*)(ws + OFF_ACC);
    uint64_t*  matrix      = (uint64_t*)(ws + OFF_MATRIX);

    score_kernel<<<(N + 3) / 4, 256, 0, stream>>>(cls, scores, coarse, fine, ctrl, rank, N);
    coarse_hist_kernel<<<256, 256, 0, stream>>>(scores, coarse, N);
    fine_hist_kernel<<<256, 256, 0, stream>>>(scores, coarse, fine, N);
    compact_kernel<<<512, 256, 0, stream>>>(scores, coarse, fine, ctrl, keys, N);
    rank_partial_kernel<<<dim3(MMAX / 256, MMAX / 256), 256, 0, stream>>>(keys, ctrl, rank);
    scatter_kernel<<<MMAX / 256, 256, 0, stream>>>(keys, rank, ctrl, boxes, csorted_idx,
                                                   csorted_box, careas);
    matrix_kernel<<<MMAX, 256, 0, stream>>>(csorted_box, careas, ctrl, matrix);
    scan_kernel<<<1, 64, 0, stream>>>(matrix, ctrl, accepted);
    output_kernel<<<(out_size + 255) / 256, 256, 0, stream>>>(boxes, cls, csorted_idx, accepted,
                                                              ctrl, out, out_size);
}